// Round 10
// baseline (152.072 us; speedup 1.0000x reference)
//
#include <hip/hip_runtime.h>
#include <hip/hip_bf16.h>
#include <stdint.h>

#define D_MODEL 1024
#define N_HEADS 16
#define N_KV 4
#define HD 64
#define BB 2
#define TT 1024
#define CACHE_LEN 1024
#define SS 2048
#define MAX_SEQ 4096
#define QKV_N 1536
#define GRP_EL (SS * HD)  // elements per (b,hkv) K or V plane

typedef __attribute__((ext_vector_type(8))) short bf16x8;
typedef __attribute__((ext_vector_type(4))) float f32x4;

__device__ inline short f2bs(float f) {
    __hip_bfloat16 h = __float2bfloat16(f);
    return *reinterpret_cast<short*>(&h);
}

#define GLDS(gp, lp) __builtin_amdgcn_global_load_lds( \
    (const __attribute__((address_space(1))) void*)(gp), \
    (__attribute__((address_space(3))) void*)(lp), 16, 0, 0)

// K fragment layout in a (b,hkv) plane: element (s,d) ->
//   (s>>4)*1024 + (d>=32)*512 + (((d&31)>>3)*16 + (s&15))*8 + (d&7)
__device__ inline int kfrag_off(int s, int d) {
    return (s >> 4) * 1024 + ((d >= 32) ? 512 : 0) + ((((d & 31) >> 3) * 16 + (s & 15)) * 8) + (d & 7);
}
// V fragment layout (32-s pair-block fills all 8 B k-slots): element (s,d) ->
//   ((s>>5)*4 + (d>>4))*512 + (((s>>2)&3)*16 + (d&15))*8 + ((s>>4)&1)*4 + (s&3)
__device__ inline int vfrag_off(int s, int d) {
    return ((s >> 5) * 4 + (d >> 4)) * 512 + ((((s >> 2) & 3) * 16 + (d & 15)) * 8)
         + (((s >> 4) & 1) * 4) + (s & 3);
}

// 32x32 fp32->bf16 transpose tile body; caller provides 32*34-short LDS
__device__ void transp_body(short* __restrict__ tile, const float* __restrict__ src,
                            short* __restrict__ dst, int N, int bx, int by) {
    int tx = threadIdx.x & 31, ty = threadIdx.x >> 5;
    int n0 = bx * 32, k0 = by * 32;
#pragma unroll
    for (int i = 0; i < 4; i++)
        tile[(ty + i * 8) * 34 + tx] = f2bs(src[(size_t)(k0 + ty + i * 8) * N + n0 + tx]);
    __syncthreads();
#pragma unroll
    for (int i = 0; i < 4; i++)
        dst[(size_t)(n0 + ty + i * 8) * 1024 + k0 + tx] = tile[tx * 34 + ty + i * 8];
}

// ---------- prep: x->bf16, Wq/Wk/Wv transposes, sincos table (gemm1 deps only) ----------
__global__ void k_prep(const float* __restrict__ x, short* __restrict__ xb,
                       const float* __restrict__ Wq, const float* __restrict__ Wk,
                       const float* __restrict__ Wv, short* __restrict__ Wt,
                       const int* __restrict__ pos,
                       float* __restrict__ costab, float* __restrict__ sintab) {
    __shared__ short tile[32 * 34];
    int id = blockIdx.x;
    int g = threadIdx.x;
    if (id < 2048) {                       // x fp32 -> bf16
        int i = (id * 256 + g) * 4;
        float4 v = *reinterpret_cast<const float4*>(x + i);
        short4 o = make_short4(f2bs(v.x), f2bs(v.y), f2bs(v.z), f2bs(v.w));
        *reinterpret_cast<short4*>(xb + i) = o;
        return;
    }
    id -= 2048;
    if (id < 1024) { transp_body(tile, Wq, Wt, 1024, id & 31, id >> 5); return; }
    id -= 1024;
    if (id < 256)  { transp_body(tile, Wk, Wt + (size_t)1024 * 1024, 256, id & 7, id >> 3); return; }
    id -= 256;
    if (id < 256)  { transp_body(tile, Wv, Wt + (size_t)1280 * 1024, 256, id & 7, id >> 3); return; }
    id -= 256;
    {                                      // sincos table [2048 rows][32 freqs]
        int p = id * 256 + g;              // over 65536
        int row = p >> 5, i = p & 31;
        int idx = pos[row] + (row & 1023) + CACHE_LEN;
        idx = min(max(idx, 0), MAX_SEQ - 1);
        float inv = expf(-(float)i * (9.210340371976184f / 32.0f));
        float sv, cv;
        sincosf((float)idx * inv, &sv, &cv);
        costab[p] = cv;
        sintab[p] = sv;
    }
}

// ---------- gemm1 (dbuf 128x64 BK=64) + RoPE/scatter epilogue + fused helper blocks ----------
// 1D grid, 3456 blocks:
//   [0,384):    gemm tile; bxg=id%24 (head col: <16 q, 16-19 k, 20-23 v), m0=(id/24)*128
//   [384,1408): Wo transpose (no gemm1 dep — backfills CUs while gemm runs)
//   [1408,3456): KV cache copy -> k_out/v_out/kf/vf
__global__ __launch_bounds__(256) void k_gemm_qkv(
    const short* __restrict__ A, const short* __restrict__ Bt,
    const float* __restrict__ costab, const float* __restrict__ sintab,
    short* __restrict__ qb, short* __restrict__ kf, short* __restrict__ vf,
    float* __restrict__ k_out, float* __restrict__ v_out,
    const float* __restrict__ Wo, short* __restrict__ Wot,
    const float* __restrict__ k_cache, const float* __restrict__ v_cache) {
    __shared__ short smem[24576];          // 48 KB
    int id = blockIdx.x;
    int g = threadIdx.x;
    if (id >= 384) {
        int hid = id - 384;
        if (hid < 1024) { transp_body(smem, Wo, Wot, 1024, hid & 31, hid >> 5); return; }
        hid -= 1024;
        int i = hid * 256 + g;             // over B*4*1024*64 = 524288
        int d = i & 63;
        int s = (i >> 6) & 1023;
        int bh = i >> 16;
        size_t cidx = ((size_t)bh * CACHE_LEN + s) * HD + d;
        size_t oidx = ((size_t)bh * SS + s) * HD + d;
        float kv = k_cache[cidx];
        float vv = v_cache[cidx];
        k_out[oidx] = kv;
        v_out[oidx] = vv;
        kf[(size_t)bh * GRP_EL + kfrag_off(s, d)] = f2bs(kv);
        vf[(size_t)bh * GRP_EL + vfrag_off(s, d)] = f2bs(vv);
        return;
    }
    // sA[buf][half]: 4096 shorts each at smem + buf*8192 + half*4096
    // sB[buf][half]: 2048 shorts each at smem + 16384 + buf*4096 + half*2048
    short* sA = smem;
    short* sB = smem + 16384;
    float* eplds = (float*)smem;           // epilogue alias (128*65 floats = 33.3 KB)
    int bxg = id % 24, byg = id / 24;
    int m0 = byg * 128, n0 = bxg * 64;
    int lane = g & 63, wave = g >> 6;
    int wr = wave >> 1, wc = wave & 1;
    int quad = lane >> 4, l15 = lane & 15;

    f32x4 acc[4][2] = {};
    int srow = (lane >> 2);
    int scol = (lane & 3) * 8;
    // 24 chunks of 1 KB per (buf,k0): 0-15 A (half=cb>>3,c=cb&7), 16-23 B (half,c of 4)
#define STAGE_G(buf, k0)                                                              \
    {                                                                                 \
        _Pragma("unroll")                                                             \
        for (int i = 0; i < 6; i++) {                                                 \
            int cb = wave * 6 + i;                                                    \
            if (cb < 16) {                                                            \
                int hh = cb >> 3, c = cb & 7;                                         \
                int row = c * 16 + srow;                                              \
                int kcol = (k0) + hh * 32 + scol;                                     \
                GLDS(A + (size_t)(m0 + row) * 1024 + kcol,                            \
                     (char*)(sA + (buf) * 8192 + hh * 4096) + c * 1024);              \
            } else {                                                                  \
                int cb2 = cb - 16;                                                    \
                int hh = cb2 >> 2, c = cb2 & 3;                                       \
                int row = c * 16 + srow;                                              \
                int kcol = (k0) + hh * 32 + scol;                                     \
                GLDS(Bt + (size_t)(n0 + row) * 1024 + kcol,                           \
                     (char*)(sB + (buf) * 4096 + hh * 2048) + c * 1024);              \
            }                                                                         \
        }                                                                             \
    }
    STAGE_G(0, 0);
    __syncthreads();
    int buf = 0;
    for (int k0 = 0; k0 < 1024; k0 += 64) {
        if (k0 + 64 < 1024) STAGE_G(buf ^ 1, k0 + 64);
#pragma unroll
        for (int h = 0; h < 2; h++) {
            bf16x8 af[4], bfr[2];
#pragma unroll
            for (int i = 0; i < 4; i++)
                af[i] = *reinterpret_cast<const bf16x8*>(
                    sA + buf * 8192 + h * 4096 + (wr * 64 + i * 16 + l15) * 32 + quad * 8);
#pragma unroll
            for (int j = 0; j < 2; j++)
                bfr[j] = *reinterpret_cast<const bf16x8*>(
                    sB + buf * 4096 + h * 2048 + (wc * 32 + j * 16 + l15) * 32 + quad * 8);
#pragma unroll
            for (int i = 0; i < 4; i++)
#pragma unroll
                for (int j = 0; j < 2; j++)
                    acc[i][j] = __builtin_amdgcn_mfma_f32_16x16x32_bf16(af[i], bfr[j], acc[i][j], 0, 0, 0);
        }
        __syncthreads();
        buf ^= 1;
    }
#pragma unroll
    for (int i = 0; i < 4; i++)
#pragma unroll
        for (int j = 0; j < 2; j++)
#pragma unroll
            for (int r = 0; r < 4; r++)
                eplds[(wr * 64 + i * 16 + quad * 4 + r) * 65 + wc * 32 + j * 16 + l15] = acc[i][j][r];
    __syncthreads();

    const float QS = 0.18033688011112042f; // 0.125 * log2(e)
    if (bxg < 20) {
        // rope: 128 rows x 32 pairs = 4096 -> 16 reps
#pragma unroll
        for (int rep = 0; rep < 16; rep++) {
            int p = rep * 256 + g;
            int row = p >> 5, i = p & 31;
            int m = m0 + row;
            int b = m >> 10, t = m & 1023;
            float cv = costab[m * 32 + i], sv = sintab[m * 32 + i];
            float x1 = eplds[row * 65 + i], x2 = eplds[row * 65 + i + 32];
            float o1 = x1 * cv - x2 * sv;
            float o2 = x2 * cv + x1 * sv;
            if (bxg < 16) {
                size_t qbase = ((size_t)(b * N_HEADS + bxg) * TT + t) * HD;
                qb[qbase + i]      = f2bs(o1 * QS);
                qb[qbase + i + 32] = f2bs(o2 * QS);
            } else {
                int h = bxg - 16;
                int s = CACHE_LEN + t;
                size_t kbase = ((size_t)(b * N_KV + h) * SS + s) * HD;
                k_out[kbase + i]      = o1;
                k_out[kbase + i + 32] = o2;
                short* kfb = kf + (size_t)(b * N_KV + h) * GRP_EL;
                kfb[kfrag_off(s, i)]      = f2bs(o1);
                kfb[kfrag_off(s, i + 32)] = f2bs(o2);
            }
        }
    } else {
        int h = bxg - 20;
        // v: 128 rows x 64 dims = 8192 -> 32 reps
#pragma unroll
        for (int rep = 0; rep < 32; rep++) {
            int p = rep * 256 + g;
            int row = p >> 6, d = p & 63;
            int m = m0 + row;
            int b = m >> 10, t = m & 1023;
            int s = CACHE_LEN + t;
            float val = eplds[row * 65 + d];
            v_out[((size_t)(b * N_KV + h) * SS + s) * HD + d] = val;
            vf[(size_t)(b * N_KV + h) * GRP_EL + vfrag_off(s, d)] = f2bs(val);
        }
    }
}

// ---------- gemm2: C[M][N] fp32 = A[M][K]bf16 * Bt[N][K]bf16 ; dbuf 128x64, BK=64 ----------
__global__ __launch_bounds__(256) void k_gemm128(
    const short* __restrict__ A, const short* __restrict__ Bt, float* __restrict__ C,
    int M, int N, int K) {
    __shared__ short smem[24576];  // 48 KB: sA 2x2x4096, sB 2x2x2048
    short* sA = smem;
    short* sB = smem + 16384;
    int m0 = blockIdx.y * 128, n0 = blockIdx.x * 64;
    int g = threadIdx.x;
    int lane = g & 63, wave = g >> 6;
    int wr = wave >> 1, wc = wave & 1;
    int quad = lane >> 4, l15 = lane & 15;

    f32x4 acc[4][2] = {};
    int srow = (lane >> 2);
    int scol = (lane & 3) * 8;
#define STAGE_W(buf, k0)                                                              \
    {                                                                                 \
        _Pragma("unroll")                                                             \
        for (int i = 0; i < 6; i++) {                                                 \
            int cb = wave * 6 + i;                                                    \
            if (cb < 16) {                                                            \
                int hh = cb >> 3, c = cb & 7;                                         \
                int row = c * 16 + srow;                                              \
                int kcol = (k0) + hh * 32 + scol;                                     \
                GLDS(A + (size_t)(m0 + row) * K + kcol,                               \
                     (char*)(sA + (buf) * 8192 + hh * 4096) + c * 1024);              \
            } else {                                                                  \
                int cb2 = cb - 16;                                                    \
                int hh = cb2 >> 2, c = cb2 & 3;                                       \
                int row = c * 16 + srow;                                              \
                int kcol = (k0) + hh * 32 + scol;                                     \
                GLDS(Bt + (size_t)(n0 + row) * K + kcol,                              \
                     (char*)(sB + (buf) * 4096 + hh * 2048) + c * 1024);              \
            }                                                                         \
        }                                                                             \
    }
    STAGE_W(0, 0);
    __syncthreads();
    int buf = 0;
    for (int k0 = 0; k0 < K; k0 += 64) {
        if (k0 + 64 < K) STAGE_W(buf ^ 1, k0 + 64);
#pragma unroll
        for (int h = 0; h < 2; h++) {
            bf16x8 af[4], bfr[2];
#pragma unroll
            for (int i = 0; i < 4; i++)
                af[i] = *reinterpret_cast<const bf16x8*>(
                    sA + buf * 8192 + h * 4096 + (wr * 64 + i * 16 + l15) * 32 + quad * 8);
#pragma unroll
            for (int j = 0; j < 2; j++)
                bfr[j] = *reinterpret_cast<const bf16x8*>(
                    sB + buf * 4096 + h * 2048 + (wc * 32 + j * 16 + l15) * 32 + quad * 8);
#pragma unroll
            for (int i = 0; i < 4; i++)
#pragma unroll
                for (int j = 0; j < 2; j++)
                    acc[i][j] = __builtin_amdgcn_mfma_f32_16x16x32_bf16(af[i], bfr[j], acc[i][j], 0, 0, 0);
        }
        __syncthreads();
        buf ^= 1;
    }
#pragma unroll
    for (int i = 0; i < 4; i++) {
        int m = m0 + wr * 64 + i * 16 + quad * 4;
#pragma unroll
        for (int j = 0; j < 2; j++) {
            int n = n0 + wc * 32 + j * 16 + l15;
#pragma unroll
            for (int r = 0; r < 4; r++)
                C[(size_t)(m + r) * N + n] = acc[i][j][r];
        }
    }
}

// ---------- attention: dbuf LDS K/V, 2 q-frags/wave, S^T=K*Q^T, full-K PV, direct out ----------
__global__ __launch_bounds__(256, 4) void k_attn(
    const short* __restrict__ qb, const short* __restrict__ kf, const short* __restrict__ vf,
    short* __restrict__ ob) {
    __shared__ short tile[2][8192]; // 2 x 16 KB: per buf [0,4096)=K, [4096,8192)=V
    int bh = blockIdx.x;
    int b = bh >> 4, h = bh & 15;
    int hkv = h >> 2;
    int lane = threadIdx.x & 63, wave = threadIdx.x >> 6;
    int quad = lane >> 4, l15 = lane & 15;
    int tw0 = blockIdx.y * 128 + wave * 16;
    int tw1 = tw0 + 64;

    const short* qrow0 = qb + ((size_t)bh * TT + tw0 + l15) * HD;
    const short* qrow1 = qb + ((size_t)bh * TT + tw1 + l15) * HD;
    bf16x8 aq00 = *reinterpret_cast<const bf16x8*>(qrow0 + quad * 8);
    bf16x8 aq01 = *reinterpret_cast<const bf16x8*>(qrow0 + 32 + quad * 8);
    bf16x8 aq10 = *reinterpret_cast<const bf16x8*>(qrow1 + quad * 8);
    bf16x8 aq11 = *reinterpret_cast<const bf16x8*>(qrow1 + 32 + quad * 8);

    const short* kfb = kf + (size_t)(b * N_KV + hkv) * GRP_EL;
    const short* vfb = vf + (size_t)(b * N_KV + hkv) * GRP_EL;

    f32x4 o0[4] = {}, o1[4] = {};
    float lr0 = 0.f, lr1 = 0.f;

#define STAGE_KV(bufi, s0)                                                    \
    {                                                                         \
        _Pragma("unroll")                                                     \
        for (int i = 0; i < 4; i++) {                                         \
            int ch = wave * 4 + i;                                            \
            const short* src = (ch < 8)                                       \
                ? kfb + ((s0) >> 4) * 1024 + ch * 512 + lane * 8              \
                : vfb + ((s0) >> 5) * 2048 + (ch - 8) * 512 + lane * 8;       \
            GLDS(src, (char*)&tile[bufi][0] + ch * 1024);                     \
        }                                                                     \
    }

    STAGE_KV(0, 0);
    __syncthreads();
    int buf = 0;
    for (int s0 = 0; s0 < SS; s0 += 64) {
        if (s0 + 64 < SS) STAGE_KV(buf ^ 1, s0 + 64);
        const short* tb = &tile[buf][0];
#pragma unroll
        for (int pp = 0; pp < 2; pp++) {
            f32x4 s0c[2], s1c[2];
#pragma unroll
            for (int ti = 0; ti < 2; ti++) {
                int nt = pp * 2 + ti;
                bf16x8 ak0 = *reinterpret_cast<const bf16x8*>(tb + nt * 1024 + lane * 8);
                bf16x8 ak1 = *reinterpret_cast<const bf16x8*>(tb + nt * 1024 + 512 + lane * 8);
                f32x4 z = {};
                z = __builtin_amdgcn_mfma_f32_16x16x32_bf16(ak0, aq00, z, 0, 0, 0);
                z = __builtin_amdgcn_mfma_f32_16x16x32_bf16(ak1, aq01, z, 0, 0, 0);
                s0c[ti] = z;
                f32x4 w = {};
                w = __builtin_amdgcn_mfma_f32_16x16x32_bf16(ak0, aq10, w, 0, 0, 0);
                w = __builtin_amdgcn_mfma_f32_16x16x32_bf16(ak1, aq11, w, 0, 0, 0);
                s1c[ti] = w;
            }
            bf16x8 bp0, bp1;
#pragma unroll
            for (int ti = 0; ti < 2; ti++)
#pragma unroll
                for (int r = 0; r < 4; r++) {
                    float p0 = exp2f(s0c[ti][r]);
                    float p1 = exp2f(s1c[ti][r]);
                    lr0 += p0;
                    lr1 += p1;
                    bp0[ti * 4 + r] = f2bs(p0);
                    bp1[ti * 4 + r] = f2bs(p1);
                }
#pragma unroll
            for (int dt = 0; dt < 4; dt++) {
                bf16x8 av = *reinterpret_cast<const bf16x8*>(
                    tb + 4096 + (pp * 4 + dt) * 512 + lane * 8);
                o0[dt] = __builtin_amdgcn_mfma_f32_16x16x32_bf16(av, bp0, o0[dt], 0, 0, 0);
                o1[dt] = __builtin_amdgcn_mfma_f32_16x16x32_bf16(av, bp1, o1[dt], 0, 0, 0);
            }
        }
        __syncthreads();
        buf ^= 1;
    }

    lr0 += __shfl_xor(lr0, 16);
    lr0 += __shfl_xor(lr0, 32);
    lr1 += __shfl_xor(lr1, 16);
    lr1 += __shfl_xor(lr1, 32);
    float inv0 = 1.0f / lr0;
    float inv1 = 1.0f / lr1;

    size_t row0 = (size_t)(b * TT) + tw0 + l15;
    size_t row1 = (size_t)(b * TT) + tw1 + l15;
#pragma unroll
    for (int dt = 0; dt < 4; dt++) {
        short4 w0 = make_short4(f2bs(o0[dt][0] * inv0), f2bs(o0[dt][1] * inv0),
                                f2bs(o0[dt][2] * inv0), f2bs(o0[dt][3] * inv0));
        short4 w1 = make_short4(f2bs(o1[dt][0] * inv1), f2bs(o1[dt][1] * inv1),
                                f2bs(o1[dt][2] * inv1), f2bs(o1[dt][3] * inv1));
        *reinterpret_cast<short4*>(ob + row0 * D_MODEL + h * 64 + dt * 16 + quad * 4) = w0;
        *reinterpret_cast<short4*>(ob + row1 * D_MODEL + h * 64 + dt * 16 + quad * 4) = w1;
    }
}

extern "C" void kernel_launch(void* const* d_in, const int* in_sizes, int n_in,
                              void* d_out, int out_size, void* d_ws, size_t ws_size,
                              hipStream_t stream) {
    (void)in_sizes; (void)n_in; (void)out_size; (void)ws_size;
    const float* x       = (const float*)d_in[0];
    const float* k_cache = (const float*)d_in[1];
    const float* v_cache = (const float*)d_in[2];
    const int*   pos     = (const int*)d_in[3];
    const float* Wq      = (const float*)d_in[4];
    const float* Wk      = (const float*)d_in[5];
    const float* Wv      = (const float*)d_in[6];
    const float* Wo      = (const float*)d_in[7];

    float* out   = (float*)d_out;
    float* k_out = out + (size_t)BB * TT * D_MODEL;
    float* v_out = k_out + (size_t)BB * N_KV * SS * HD;

    char* ws = (char*)d_ws;
    short* xb     = (short*)(ws);                 // [0,4) MB
    short* Wt     = (short*)(ws + (4u << 20));    // [4,7)
    float* costab = (float*)(ws + (7u << 20));    // [7,7.25)
    float* sintab = (float*)(ws + (7u << 20) + (256u << 10)); // [7.25,7.5)
    short* qbuf   = (short*)(ws + (8u << 20));    // [8,12)
    short* kfr    = (short*)(ws + (12u << 20));   // [12,14)
    short* vfr    = (short*)(ws + (14u << 20));   // [14,16)
    short* obuf   = (short*)(ws + (16u << 20));   // [16,20)
    short* Wot    = (short*)(ws + (20u << 20));   // [20,22)

    k_prep<<<3840, 256, 0, stream>>>(x, xb, Wq, Wk, Wv, Wt, pos, costab, sintab);

    k_gemm_qkv<<<3456, 256, 0, stream>>>(
        xb, Wt, costab, sintab, qbuf, kfr, vfr, k_out, v_out,
        Wo, Wot, k_cache, v_cache);

    k_attn<<<dim3(32, TT / 128), 256, 0, stream>>>(qbuf, kfr, vfr, obuf);

    k_gemm128<<<dim3(1024 / 64, 2048 / 128), 256, 0, stream>>>(
        obuf, Wot, (float*)d_out, 2048, 1024, 1024);
}

// Round 11
// 145.904 us; speedup vs baseline: 1.0423x; 1.0423x over previous
//
#include <hip/hip_runtime.h>
#include <hip/hip_bf16.h>
#include <stdint.h>

#define D_MODEL 1024
#define N_HEADS 16
#define N_KV 4
#define HD 64
#define BB 2
#define TT 1024
#define CACHE_LEN 1024
#define SS 2048
#define MAX_SEQ 4096
#define QKV_N 1536
#define GRP_EL (SS * HD)  // elements per (b,hkv) K or V plane

typedef __attribute__((ext_vector_type(8))) short bf16x8;
typedef __attribute__((ext_vector_type(4))) float f32x4;

__device__ inline short f2bs(float f) {
    __hip_bfloat16 h = __float2bfloat16(f);
    return *reinterpret_cast<short*>(&h);
}

#define GLDS(gp, lp) __builtin_amdgcn_global_load_lds( \
    (const __attribute__((address_space(1))) void*)(gp), \
    (__attribute__((address_space(3))) void*)(lp), 16, 0, 0)

// K fragment layout in a (b,hkv) plane: element (s,d) ->
//   (s>>4)*1024 + (d>=32)*512 + (((d&31)>>3)*16 + (s&15))*8 + (d&7)
__device__ inline int kfrag_off(int s, int d) {
    return (s >> 4) * 1024 + ((d >= 32) ? 512 : 0) + ((((d & 31) >> 3) * 16 + (s & 15)) * 8) + (d & 7);
}
// V fragment layout (32-s pair-block fills all 8 B k-slots): element (s,d) ->
//   ((s>>5)*4 + (d>>4))*512 + (((s>>2)&3)*16 + (d&15))*8 + ((s>>4)&1)*4 + (s&3)
__device__ inline int vfrag_off(int s, int d) {
    return ((s >> 5) * 4 + (d >> 4)) * 512 + ((((s >> 2) & 3) * 16 + (d & 15)) * 8)
         + (((s >> 4) & 1) * 4) + (s & 3);
}

// 32x32 fp32->bf16 transpose tile body; caller provides 32*34-short LDS
__device__ void transp_body(short* __restrict__ tile, const float* __restrict__ src,
                            short* __restrict__ dst, int N, int bx, int by) {
    int tx = threadIdx.x & 31, ty = threadIdx.x >> 5;
    int n0 = bx * 32, k0 = by * 32;
#pragma unroll
    for (int i = 0; i < 4; i++)
        tile[(ty + i * 8) * 34 + tx] = f2bs(src[(size_t)(k0 + ty + i * 8) * N + n0 + tx]);
    __syncthreads();
#pragma unroll
    for (int i = 0; i < 4; i++)
        dst[(size_t)(n0 + ty + i * 8) * 1024 + k0 + tx] = tile[tx * 34 + ty + i * 8];
}

// ---------- prep: x->bf16, Wq/Wk/Wv transposes, sincos table (gemm1 deps only) ----------
__global__ void k_prep(const float* __restrict__ x, short* __restrict__ xb,
                       const float* __restrict__ Wq, const float* __restrict__ Wk,
                       const float* __restrict__ Wv, short* __restrict__ Wt,
                       const int* __restrict__ pos,
                       float* __restrict__ costab, float* __restrict__ sintab) {
    __shared__ short tile[32 * 34];
    int id = blockIdx.x;
    int g = threadIdx.x;
    if (id < 2048) {                       // x fp32 -> bf16
        int i = (id * 256 + g) * 4;
        float4 v = *reinterpret_cast<const float4*>(x + i);
        short4 o = make_short4(f2bs(v.x), f2bs(v.y), f2bs(v.z), f2bs(v.w));
        *reinterpret_cast<short4*>(xb + i) = o;
        return;
    }
    id -= 2048;
    if (id < 1024) { transp_body(tile, Wq, Wt, 1024, id & 31, id >> 5); return; }
    id -= 1024;
    if (id < 256)  { transp_body(tile, Wk, Wt + (size_t)1024 * 1024, 256, id & 7, id >> 3); return; }
    id -= 256;
    if (id < 256)  { transp_body(tile, Wv, Wt + (size_t)1280 * 1024, 256, id & 7, id >> 3); return; }
    id -= 256;
    {                                      // sincos table [2048 rows][32 freqs]
        int p = id * 256 + g;              // over 65536
        int row = p >> 5, i = p & 31;
        int idx = pos[row] + (row & 1023) + CACHE_LEN;
        idx = min(max(idx, 0), MAX_SEQ - 1);
        float inv = expf(-(float)i * (9.210340371976184f / 32.0f));
        float sv, cv;
        sincosf((float)idx * inv, &sv, &cv);
        costab[p] = cv;
        sintab[p] = sv;
    }
}

// ---------- gemm1 (dbuf 64x64 BK=64) + RoPE/scatter epilogue + fused helper blocks ----------
// 1D grid, 3840 blocks:
//   [0,768):    gemm tile; bxg=id%24 (head col: <16 q, 16-19 k, 20-23 v), byg=id/24 (m-tile)
//   [768,1792): Wo transpose (no gemm1 dep — backfills CU slots while gemm drains)
//   [1792,3840): KV cache copy -> k_out/v_out/kf/vf
__global__ __launch_bounds__(256) void k_gemm_qkv(
    const short* __restrict__ A, const short* __restrict__ Bt,
    const float* __restrict__ costab, const float* __restrict__ sintab,
    short* __restrict__ qb, short* __restrict__ kf, short* __restrict__ vf,
    float* __restrict__ k_out, float* __restrict__ v_out,
    const float* __restrict__ Wo, short* __restrict__ Wot,
    const float* __restrict__ k_cache, const float* __restrict__ v_cache) {
    __shared__ short smem[16384];          // 32 KB: sA[2][2][2048] | sB[2][2][2048]
    int id = blockIdx.x;
    int g = threadIdx.x;
    if (id >= 768) {
        int hid = id - 768;
        if (hid < 1024) { transp_body(smem, Wo, Wot, 1024, hid & 31, hid >> 5); return; }
        hid -= 1024;
        int i = hid * 256 + g;             // over B*4*1024*64 = 524288
        int d = i & 63;
        int s = (i >> 6) & 1023;
        int bh = i >> 16;
        size_t cidx = ((size_t)bh * CACHE_LEN + s) * HD + d;
        size_t oidx = ((size_t)bh * SS + s) * HD + d;
        float kv = k_cache[cidx];
        float vv = v_cache[cidx];
        k_out[oidx] = kv;
        v_out[oidx] = vv;
        kf[(size_t)bh * GRP_EL + kfrag_off(s, d)] = f2bs(kv);
        vf[(size_t)bh * GRP_EL + vfrag_off(s, d)] = f2bs(vv);
        return;
    }
    short* sA = smem;
    short* sB = smem + 8192;
    float* eplds = (float*)smem;           // epilogue alias (64*65 floats)
    int bxg = id % 24, byg = id / 24;
    int m0 = byg * 64, n0 = bxg * 64;
    int lane = g & 63, wave = g >> 6;
    int wr = wave >> 1, wc = wave & 1;
    int quad = lane >> 4, l15 = lane & 15;

    f32x4 acc[2][2] = {};
    int srow = (lane >> 2);
    int scol = (lane & 3) * 8;
#define STAGE_G(buf, k0)                                                              \
    {                                                                                 \
        _Pragma("unroll")                                                             \
        for (int i = 0; i < 2; i++) {                                                 \
            int cb = wave * 2 + i;                                                    \
            int h = cb >> 2, c = cb & 3;                                              \
            int row = c * 16 + srow;                                                  \
            int kcol = (k0) + h * 32 + scol;                                          \
            GLDS(A + (size_t)(m0 + row) * 1024 + kcol,                                \
                 (char*)(sA + (buf) * 4096 + h * 2048) + c * 1024);                   \
            GLDS(Bt + (size_t)(n0 + row) * 1024 + kcol,                               \
                 (char*)(sB + (buf) * 4096 + h * 2048) + c * 1024);                   \
        }                                                                             \
    }
    STAGE_G(0, 0);
    __syncthreads();
    int buf = 0;
    for (int k0 = 0; k0 < 1024; k0 += 64) {
        if (k0 + 64 < 1024) STAGE_G(buf ^ 1, k0 + 64);
#pragma unroll
        for (int h = 0; h < 2; h++) {
            bf16x8 af[2], bfr[2];
#pragma unroll
            for (int i = 0; i < 2; i++)
                af[i] = *reinterpret_cast<const bf16x8*>(
                    sA + buf * 4096 + h * 2048 + (wr * 32 + i * 16 + l15) * 32 + quad * 8);
#pragma unroll
            for (int j = 0; j < 2; j++)
                bfr[j] = *reinterpret_cast<const bf16x8*>(
                    sB + buf * 4096 + h * 2048 + (wc * 32 + j * 16 + l15) * 32 + quad * 8);
#pragma unroll
            for (int i = 0; i < 2; i++)
#pragma unroll
                for (int j = 0; j < 2; j++)
                    acc[i][j] = __builtin_amdgcn_mfma_f32_16x16x32_bf16(af[i], bfr[j], acc[i][j], 0, 0, 0);
        }
        __syncthreads();
        buf ^= 1;
    }
#pragma unroll
    for (int i = 0; i < 2; i++)
#pragma unroll
        for (int j = 0; j < 2; j++)
#pragma unroll
            for (int r = 0; r < 4; r++)
                eplds[(wr * 32 + i * 16 + quad * 4 + r) * 65 + wc * 32 + j * 16 + l15] = acc[i][j][r];
    __syncthreads();

    const float QS = 0.18033688011112042f; // 0.125 * log2(e)
    if (bxg < 20) {
#pragma unroll
        for (int rep = 0; rep < 8; rep++) {
            int p = rep * 256 + g;
            int row = p >> 5, i = p & 31;
            int m = m0 + row;
            int b = m >> 10, t = m & 1023;
            float cv = costab[m * 32 + i], sv = sintab[m * 32 + i];
            float x1 = eplds[row * 65 + i], x2 = eplds[row * 65 + i + 32];
            float o1 = x1 * cv - x2 * sv;
            float o2 = x2 * cv + x1 * sv;
            if (bxg < 16) {
                size_t qbase = ((size_t)(b * N_HEADS + bxg) * TT + t) * HD;
                qb[qbase + i]      = f2bs(o1 * QS);
                qb[qbase + i + 32] = f2bs(o2 * QS);
            } else {
                int h = bxg - 16;
                int s = CACHE_LEN + t;
                size_t kbase = ((size_t)(b * N_KV + h) * SS + s) * HD;
                k_out[kbase + i]      = o1;
                k_out[kbase + i + 32] = o2;
                short* kfb = kf + (size_t)(b * N_KV + h) * GRP_EL;
                kfb[kfrag_off(s, i)]      = f2bs(o1);
                kfb[kfrag_off(s, i + 32)] = f2bs(o2);
            }
        }
    } else {
        int h = bxg - 20;
#pragma unroll
        for (int rep = 0; rep < 16; rep++) {
            int p = rep * 256 + g;
            int row = p >> 6, d = p & 63;
            int m = m0 + row;
            int b = m >> 10, t = m & 1023;
            int s = CACHE_LEN + t;
            float val = eplds[row * 65 + d];
            v_out[((size_t)(b * N_KV + h) * SS + s) * HD + d] = val;
            vf[(size_t)(b * N_KV + h) * GRP_EL + vfrag_off(s, d)] = f2bs(val);
        }
    }
}

// ---------- gemm2: C[M][N] fp32 = A[M][K]bf16 * Bt[N][K]bf16 ; dbuf 64x64, BK=64 ----------
__global__ __launch_bounds__(256) void k_gemm64(
    const short* __restrict__ A, const short* __restrict__ Bt, float* __restrict__ C,
    int M, int N, int K) {
    __shared__ short sA[2][2][2048];
    __shared__ short sB[2][2][2048];
    int m0 = blockIdx.y * 64, n0 = blockIdx.x * 64;
    int g = threadIdx.x;
    int lane = g & 63, wave = g >> 6;
    int wr = wave >> 1, wc = wave & 1;
    int quad = lane >> 4, l15 = lane & 15;

    f32x4 acc[2][2] = {};
    int srow = (lane >> 2);
    int scol = (lane & 3) * 8;
#define STAGE_W(buf, k0)                                                             \
    {                                                                                \
        _Pragma("unroll")                                                            \
        for (int i = 0; i < 2; i++) {                                                \
            int cb = wave * 2 + i;                                                   \
            int h = cb >> 2, c = cb & 3;                                             \
            int row = c * 16 + srow;                                                 \
            int kcol = (k0) + h * 32 + scol;                                         \
            GLDS(A + (size_t)(m0 + row) * K + kcol, (char*)&sA[buf][h][0] + c * 1024);\
            GLDS(Bt + (size_t)(n0 + row) * K + kcol, (char*)&sB[buf][h][0] + c * 1024);\
        }                                                                            \
    }
    STAGE_W(0, 0);
    __syncthreads();
    int buf = 0;
    for (int k0 = 0; k0 < K; k0 += 64) {
        if (k0 + 64 < K) STAGE_W(buf ^ 1, k0 + 64);
#pragma unroll
        for (int h = 0; h < 2; h++) {
            bf16x8 af[2], bfr[2];
#pragma unroll
            for (int i = 0; i < 2; i++)
                af[i] = *reinterpret_cast<const bf16x8*>(&sA[buf][h][(wr * 32 + i * 16 + l15) * 32 + quad * 8]);
#pragma unroll
            for (int j = 0; j < 2; j++)
                bfr[j] = *reinterpret_cast<const bf16x8*>(&sB[buf][h][(wc * 32 + j * 16 + l15) * 32 + quad * 8]);
#pragma unroll
            for (int i = 0; i < 2; i++)
#pragma unroll
                for (int j = 0; j < 2; j++)
                    acc[i][j] = __builtin_amdgcn_mfma_f32_16x16x32_bf16(af[i], bfr[j], acc[i][j], 0, 0, 0);
        }
        __syncthreads();
        buf ^= 1;
    }
#pragma unroll
    for (int i = 0; i < 2; i++) {
        int m = m0 + wr * 32 + i * 16 + quad * 4;
#pragma unroll
        for (int j = 0; j < 2; j++) {
            int n = n0 + wc * 32 + j * 16 + l15;
#pragma unroll
            for (int r = 0; r < 4; r++)
                C[(size_t)(m + r) * N + n] = acc[i][j][r];
        }
    }
}

// ---------- attention: dbuf LDS K/V, 2 q-frags/wave, S^T=K*Q^T, full-K PV, direct out ----------
__global__ __launch_bounds__(256, 4) void k_attn(
    const short* __restrict__ qb, const short* __restrict__ kf, const short* __restrict__ vf,
    short* __restrict__ ob) {
    __shared__ short tile[2][8192]; // 2 x 16 KB: per buf [0,4096)=K, [4096,8192)=V
    int bh = blockIdx.x;
    int b = bh >> 4, h = bh & 15;
    int hkv = h >> 2;
    int lane = threadIdx.x & 63, wave = threadIdx.x >> 6;
    int quad = lane >> 4, l15 = lane & 15;
    int tw0 = blockIdx.y * 128 + wave * 16;
    int tw1 = tw0 + 64;

    const short* qrow0 = qb + ((size_t)bh * TT + tw0 + l15) * HD;
    const short* qrow1 = qb + ((size_t)bh * TT + tw1 + l15) * HD;
    bf16x8 aq00 = *reinterpret_cast<const bf16x8*>(qrow0 + quad * 8);
    bf16x8 aq01 = *reinterpret_cast<const bf16x8*>(qrow0 + 32 + quad * 8);
    bf16x8 aq10 = *reinterpret_cast<const bf16x8*>(qrow1 + quad * 8);
    bf16x8 aq11 = *reinterpret_cast<const bf16x8*>(qrow1 + 32 + quad * 8);

    const short* kfb = kf + (size_t)(b * N_KV + hkv) * GRP_EL;
    const short* vfb = vf + (size_t)(b * N_KV + hkv) * GRP_EL;

    f32x4 o0[4] = {}, o1[4] = {};
    float lr0 = 0.f, lr1 = 0.f;

#define STAGE_KV(bufi, s0)                                                    \
    {                                                                         \
        _Pragma("unroll")                                                     \
        for (int i = 0; i < 4; i++) {                                         \
            int ch = wave * 4 + i;                                            \
            const short* src = (ch < 8)                                       \
                ? kfb + ((s0) >> 4) * 1024 + ch * 512 + lane * 8              \
                : vfb + ((s0) >> 5) * 2048 + (ch - 8) * 512 + lane * 8;       \
            GLDS(src, (char*)&tile[bufi][0] + ch * 1024);                     \
        }                                                                     \
    }

    STAGE_KV(0, 0);
    __syncthreads();
    int buf = 0;
    for (int s0 = 0; s0 < SS; s0 += 64) {
        if (s0 + 64 < SS) STAGE_KV(buf ^ 1, s0 + 64);
        const short* tb = &tile[buf][0];
#pragma unroll
        for (int pp = 0; pp < 2; pp++) {
            f32x4 s0c[2], s1c[2];
#pragma unroll
            for (int ti = 0; ti < 2; ti++) {
                int nt = pp * 2 + ti;
                bf16x8 ak0 = *reinterpret_cast<const bf16x8*>(tb + nt * 1024 + lane * 8);
                bf16x8 ak1 = *reinterpret_cast<const bf16x8*>(tb + nt * 1024 + 512 + lane * 8);
                f32x4 z = {};
                z = __builtin_amdgcn_mfma_f32_16x16x32_bf16(ak0, aq00, z, 0, 0, 0);
                z = __builtin_amdgcn_mfma_f32_16x16x32_bf16(ak1, aq01, z, 0, 0, 0);
                s0c[ti] = z;
                f32x4 w = {};
                w = __builtin_amdgcn_mfma_f32_16x16x32_bf16(ak0, aq10, w, 0, 0, 0);
                w = __builtin_amdgcn_mfma_f32_16x16x32_bf16(ak1, aq11, w, 0, 0, 0);
                s1c[ti] = w;
            }
            bf16x8 bp0, bp1;
#pragma unroll
            for (int ti = 0; ti < 2; ti++)
#pragma unroll
                for (int r = 0; r < 4; r++) {
                    float p0 = exp2f(s0c[ti][r]);
                    float p1 = exp2f(s1c[ti][r]);
                    lr0 += p0;
                    lr1 += p1;
                    bp0[ti * 4 + r] = f2bs(p0);
                    bp1[ti * 4 + r] = f2bs(p1);
                }
#pragma unroll
            for (int dt = 0; dt < 4; dt++) {
                bf16x8 av = *reinterpret_cast<const bf16x8*>(
                    tb + 4096 + (pp * 4 + dt) * 512 + lane * 8);
                o0[dt] = __builtin_amdgcn_mfma_f32_16x16x32_bf16(av, bp0, o0[dt], 0, 0, 0);
                o1[dt] = __builtin_amdgcn_mfma_f32_16x16x32_bf16(av, bp1, o1[dt], 0, 0, 0);
            }
        }
        __syncthreads();
        buf ^= 1;
    }

    lr0 += __shfl_xor(lr0, 16);
    lr0 += __shfl_xor(lr0, 32);
    lr1 += __shfl_xor(lr1, 16);
    lr1 += __shfl_xor(lr1, 32);
    float inv0 = 1.0f / lr0;
    float inv1 = 1.0f / lr1;

    size_t row0 = (size_t)(b * TT) + tw0 + l15;
    size_t row1 = (size_t)(b * TT) + tw1 + l15;
#pragma unroll
    for (int dt = 0; dt < 4; dt++) {
        short4 w0 = make_short4(f2bs(o0[dt][0] * inv0), f2bs(o0[dt][1] * inv0),
                                f2bs(o0[dt][2] * inv0), f2bs(o0[dt][3] * inv0));
        short4 w1 = make_short4(f2bs(o1[dt][0] * inv1), f2bs(o1[dt][1] * inv1),
                                f2bs(o1[dt][2] * inv1), f2bs(o1[dt][3] * inv1));
        *reinterpret_cast<short4*>(ob + row0 * D_MODEL + h * 64 + dt * 16 + quad * 4) = w0;
        *reinterpret_cast<short4*>(ob + row1 * D_MODEL + h * 64 + dt * 16 + quad * 4) = w1;
    }
}

extern "C" void kernel_launch(void* const* d_in, const int* in_sizes, int n_in,
                              void* d_out, int out_size, void* d_ws, size_t ws_size,
                              hipStream_t stream) {
    (void)in_sizes; (void)n_in; (void)out_size; (void)ws_size;
    const float* x       = (const float*)d_in[0];
    const float* k_cache = (const float*)d_in[1];
    const float* v_cache = (const float*)d_in[2];
    const int*   pos     = (const int*)d_in[3];
    const float* Wq      = (const float*)d_in[4];
    const float* Wk      = (const float*)d_in[5];
    const float* Wv      = (const float*)d_in[6];
    const float* Wo      = (const float*)d_in[7];

    float* out   = (float*)d_out;
    float* k_out = out + (size_t)BB * TT * D_MODEL;
    float* v_out = k_out + (size_t)BB * N_KV * SS * HD;

    char* ws = (char*)d_ws;
    short* xb     = (short*)(ws);                 // [0,4) MB
    short* Wt     = (short*)(ws + (4u << 20));    // [4,7)
    float* costab = (float*)(ws + (7u << 20));    // [7,7.25)
    float* sintab = (float*)(ws + (7u << 20) + (256u << 10)); // [7.25,7.5)
    short* qbuf   = (short*)(ws + (8u << 20));    // [8,12)
    short* kfr    = (short*)(ws + (12u << 20));   // [12,14)
    short* vfr    = (short*)(ws + (14u << 20));   // [14,16)
    short* obuf   = (short*)(ws + (16u << 20));   // [16,20)
    short* Wot    = (short*)(ws + (20u << 20));   // [20,22)

    k_prep<<<3840, 256, 0, stream>>>(x, xb, Wq, Wk, Wv, Wt, pos, costab, sintab);

    k_gemm_qkv<<<3840, 256, 0, stream>>>(
        xb, Wt, costab, sintab, qbuf, kfr, vfr, k_out, v_out,
        Wo, Wot, k_cache, v_cache);

    k_attn<<<dim3(32, TT / 128), 256, 0, stream>>>(qbuf, kfr, vfr, obuf);

    k_gemm64<<<dim3(1024 / 64, 2048 / 64), 256, 0, stream>>>(
        obuf, Wot, (float*)d_out, 2048, 1024, 1024);
}